// Round 2
// baseline (268.016 us; speedup 1.0000x reference)
//
#include <hip/hip_runtime.h>

#define NN 256
#define CC 16
#define OO 16
#define BB 16
#define NTILE 16
#define NPAIRS 136   // NTILE*(NTILE+1)/2

// workspace layout (float offsets)
#define OFF_DIAG  0          // B*C*N*2 = 131072
#define OFF_ROW   131072     // 131072
#define OFF_COL0  262144     // 131072 (rows 0..127 partial)
#define OFF_COL1  393216     // 131072 (rows 128..255 partial)
#define OFF_TOT0  524288     // 512
#define OFF_TOT1  524800     // 512
#define OFF_DSUM0 525312     // 512
#define OFF_DSUM1 525824     // 512
#define OFF_RI    526336     // B*O*N*2 = 131072 (includes S0 fold)
#define OFF_CJ    657408     // 131072
#define OFF_DM    788480     // 131072

typedef float v2f __attribute__((ext_vector_type(2)));   // -> v_pk_*_f32

__device__ __forceinline__ v2f nt_loadv(const float2* p) {
    double d = __builtin_nontemporal_load((const double*)p);
    v2f r; __builtin_memcpy(&r, &d, 8); return r;
}
__device__ __forceinline__ void nt_storev(float2* p, v2f v) {
    double d; __builtin_memcpy(&d, &v, 8);
    __builtin_nontemporal_store(d, (double*)p);
}
__device__ __forceinline__ v2f ld2(const float* p) {
    v2f r; __builtin_memcpy(&r, p, 8); return r;
}

// ---------------------------------------------------------------------------
// Kernel 1: per-(b,c,row-half) reductions. 512 blocks (2 per slice) x 1024
// threads. Each block handles 128 rows; col/tot/dsum stored as per-half
// partials merged in k_terms. Normal (caching) loads on purpose: this pass
// populates L3 for k_main.
// ---------------------------------------------------------------------------
__global__ __launch_bounds__(1024) void k_reduce(const float* __restrict__ in,
                                                 float* __restrict__ ws) {
    float* diagA = ws + OFF_DIAG;
    float* rowA  = ws + OFF_ROW;

    const int bid  = blockIdx.x;
    const int bc   = bid >> 1;
    const int half = bid & 1;
    float* colH  = ws + (half ? OFF_COL1 : OFF_COL0);
    float* totH  = ws + (half ? OFF_TOT1 : OFF_TOT0);
    float* dsumH = ws + (half ? OFF_DSUM1 : OFF_DSUM0);

    const int tid = threadIdx.x;
    const int wv  = tid >> 6;
    const int ln  = tid & 63;

    const float* base = in + (size_t)bc * (NN * NN * 2) + (size_t)half * (128 * NN * 2);

    __shared__ float colLDS[16][512];
    __shared__ float rowLDS[256];
    __shared__ float diagLDS[256];
    __shared__ float redT[16][2];
    __shared__ float redD[16][2];

    float a0 = 0, a1 = 0, a2 = 0, a3 = 0;
    float b0 = 0, b1 = 0, b2 = 0, b3 = 0;
    float dsx = 0, dsy = 0;

#pragma unroll 2
    for (int k = 0; k < 8; k++) {
        const int i = wv + 16 * k;           // local row 0..127
        const int g = (half << 7) + i;       // global row 0..255
        const float4* rowp = (const float4*)(base + i * (NN * 2));
        float4 v0 = rowp[ln];
        float4 v1 = rowp[64 + ln];
        a0 += v0.x; a1 += v0.y; a2 += v0.z; a3 += v0.w;
        b0 += v1.x; b1 += v1.y; b2 += v1.z; b3 += v1.w;
        float sx = v0.x + v0.z + v1.x + v1.z;
        float sy = v0.y + v0.w + v1.y + v1.w;
#pragma unroll
        for (int off = 32; off >= 1; off >>= 1) {
            sx += __shfl_xor(sx, off);
            sy += __shfl_xor(sy, off);
        }
        if (ln == 0) { rowLDS[2 * i] = sx; rowLDS[2 * i + 1] = sy; }
        const int k4 = g >> 1;               // float4 index of diag elem
        if (ln == (k4 & 63)) {
            float4 dv = (k4 & 64) ? v1 : v0;
            float dx = (g & 1) ? dv.z : dv.x;
            float dy = (g & 1) ? dv.w : dv.y;
            diagLDS[2 * i] = dx; diagLDS[2 * i + 1] = dy;
            dsx += dx; dsy += dy;
        }
    }
    ((float4*)&colLDS[wv][0])[ln]   = make_float4(a0, a1, a2, a3);
    ((float4*)&colLDS[wv][256])[ln] = make_float4(b0, b1, b2, b3);

#pragma unroll
    for (int off = 32; off >= 1; off >>= 1) {
        dsx += __shfl_xor(dsx, off);
        dsy += __shfl_xor(dsy, off);
    }
    if (ln == 0) { redD[wv][0] = dsx; redD[wv][1] = dsy; }
    __syncthreads();

    float totpart = 0.f;
    if (tid < 512) {
        float s = 0.f;
#pragma unroll
        for (int w2 = 0; w2 < 16; w2++) s += colLDS[w2][tid];
        colH[bc * 512 + tid] = s;
        totpart = s;
    }
    if (tid < 256) {
        rowA[bc * 512 + half * 256 + tid]  = rowLDS[tid];
        diagA[bc * 512 + half * 256 + tid] = diagLDS[tid];
    }
#pragma unroll
    for (int off = 32; off >= 2; off >>= 1) totpart += __shfl_xor(totpart, off);
    if (ln < 2) redT[wv][ln] = totpart;
    __syncthreads();
    if (tid == 0) {
        float t0 = 0, t1 = 0, d0 = 0, d1 = 0;
        for (int w2 = 0; w2 < 16; w2++) {
            t0 += redT[w2][0]; t1 += redT[w2][1];
            d0 += redD[w2][0]; d1 += redD[w2][1];
        }
        totH[bc * 2]  = t0; totH[bc * 2 + 1]  = t1;
        dsumH[bc * 2] = d0; dsumH[bc * 2 + 1] = d1;
    }
}

// ---------------------------------------------------------------------------
// Kernel 2: build broadcast terms Ri (with S0 folded in), Cj, Dm (B,O,N,2).
// Merges the per-half col/tot/dsum partials from k_reduce.
// ---------------------------------------------------------------------------
__global__ __launch_bounds__(256) void k_terms(const float* __restrict__ w,
                                               float* __restrict__ ws) {
    const float* diagA = ws + OFF_DIAG;
    const float* rowA  = ws + OFF_ROW;
    const float* colA0 = ws + OFF_COL0;
    const float* colA1 = ws + OFF_COL1;
    const float* tot0  = ws + OFF_TOT0;
    const float* tot1  = ws + OFF_TOT1;
    const float* dsm0  = ws + OFF_DSUM0;
    const float* dsm1  = ws + OFF_DSUM1;
    float* RiA = ws + OFF_RI;
    float* CjA = ws + OFF_CJ;
    float* DmA = ws + OFF_DM;

    const int b = blockIdx.x >> 4;
    const int o = blockIdx.x & 15;
    const int m = threadIdx.x;

    __shared__ float wL[CC][15];
    if (m < CC * 15) wL[m / 15][m % 15] = w[(m / 15) * (OO * 15) + o * 15 + m % 15];
    __syncthreads();

    float rix = 0, riy = 0, cjx = 0, cjy = 0, dmx = 0, dmy = 0;
    float s0x = 0, s0y = 0, dcx = 0, dcy = 0;
#pragma unroll
    for (int c = 0; c < CC; c++) {
        int bcm = (b * CC + c) * NN + m;
        float2 dg = ((const float2*)diagA)[bcm];
        float2 c0 = ((const float2*)colA0)[bcm];
        float2 c1 = ((const float2*)colA1)[bcm];
        float2 rs = ((const float2*)rowA)[bcm];
        float csx = c0.x + c1.x, csy = c0.y + c1.y;
        float w4 = wL[c][4], w5 = wL[c][5], w6 = wL[c][6];
        float w7 = wL[c][7], w8 = wL[c][8], w9 = wL[c][9];
        float wa = wL[c][10], wb = wL[c][11], wc = wL[c][12];
        rix += w6 * dg.x + w9 * csx + wc * rs.x;
        riy += w6 * dg.y + w9 * csy + wc * rs.y;
        cjx += w5 * dg.x + w8 * csx + wb * rs.x;
        cjy += w5 * dg.y + w8 * csy + wb * rs.y;
        dmx += w4 * dg.x + w7 * csx + wa * rs.x;
        dmy += w4 * dg.y + w7 * csy + wa * rs.y;
        float2 ta = ((const float2*)tot0)[b * CC + c];
        float2 tb = ((const float2*)tot1)[b * CC + c];
        float2 da = ((const float2*)dsm0)[b * CC + c];
        float2 db = ((const float2*)dsm1)[b * CC + c];
        float vx = (da.x + db.x) * (1.0f / NN) + ta.x + tb.x;
        float vy = (da.y + db.y) * (1.0f / NN) + ta.y + tb.y;
        s0x += wL[c][0] * vx; s0y += wL[c][0] * vy;
        dcx += wL[c][1] * vx; dcy += wL[c][1] * vy;
    }
    int om = (b * OO + o) * NN + m;
    ((float2*)RiA)[om] = make_float2(rix + s0x, riy + s0y);   // S0 folded into Ri
    ((float2*)CjA)[om] = make_float2(cjx, cjy);
    ((float2*)DmA)[om] = make_float2(dmx + dcx, dmy + dcy);
}

// ---------------------------------------------------------------------------
// Kernel 3: main pass. One block per (b, tile-pair (I,J), I<=J).
// Changes vs 266us baseline: packed-f32 (v2f) accumulators; o-chunked
// transpose exchange (8 o's, stride 18 floats -> 18 KiB instead of 34 KiB
// LDS); S0 pre-folded into Ri; __launch_bounds__(256,4) for 4 blocks/CU.
// NT loads (input stays L3-resident) + NT stores (streaming output).
// ---------------------------------------------------------------------------
__global__ __launch_bounds__(256, 4) void k_main(const float* __restrict__ in,
                                                 const float* __restrict__ w,
                                                 float* __restrict__ out,
                                                 const float* __restrict__ ws) {
    const float* RiA = ws + OFF_RI;
    const float* CjA = ws + OFF_CJ;
    const float* DmA = ws + OFF_DM;

    const int b = blockIdx.x / NPAIRS;
    int p = blockIdx.x % NPAIRS;
    int I = 0;
    { int cnt = NTILE; while (p >= cnt) { p -= cnt; cnt--; I++; } }
    const int J = I + p;

    const int tid = threadIdx.x;
    const int ti = tid >> 4;
    const int tj = tid & 15;

    __shared__ __align__(16) float xch[256 * 18];   // 8 o x float2 + 2 pad
    __shared__ float wsm[256];                      // w13 [c][o]
    __shared__ v2f RiI[16][16];
    __shared__ v2f CjJ[16][16];
    __shared__ v2f RiJ[16][16];
    __shared__ v2f CjI[16][16];

    {
        wsm[tid] = w[tid * 15 + 13];
        RiI[ti][tj] = ld2(RiA + 2 * ((b * OO + ti) * NN + I * 16 + tj));
        CjJ[ti][tj] = ld2(CjA + 2 * ((b * OO + ti) * NN + J * 16 + tj));
        if (I != J) {
            RiJ[ti][tj] = ld2(RiA + 2 * ((b * OO + ti) * NN + J * 16 + tj));
            CjI[ti][tj] = ld2(CjA + 2 * ((b * OO + ti) * NN + I * 16 + tj));
        }
    }
    __syncthreads();

    v2f P[16], Q[16];
#pragma unroll
    for (int o = 0; o < 16; o++) { P[o] = (v2f)(0.f); Q[o] = (v2f)(0.f); }

    const float2* pA = (const float2*)in + ((size_t)(b * CC) * NN + I * 16 + ti) * NN + J * 16 + tj;
    const float2* pB = (const float2*)in + ((size_t)(b * CC) * NN + J * 16 + ti) * NN + I * 16 + tj;

#pragma unroll 4
    for (int c = 0; c < CC; c++) {
        v2f a  = nt_loadv(&pA[(size_t)c * (NN * NN)]);
        v2f bb = nt_loadv(&pB[(size_t)c * (NN * NN)]);
#pragma unroll
        for (int o = 0; o < 16; o++) {
            float wv = wsm[c * 16 + o];
            P[o] += wv * a;     // v_pk_fma_f32
            Q[o] += wv * bb;
        }
    }

    const int sidx = ti * 16 + (tj ^ ti);
    const int ridx = tj * 16 + (ti ^ tj);
    const bool dgl = (I == J) && (ti == tj);
    float2* out2 = (float2*)out;

    // ---- phase 1: out(I,J) = P + Q^T + terms (o in chunks of 8) ----
    {
        const int gi = I * 16 + ti, gj = J * 16 + tj;
        for (int oc = 0; oc < 16; oc += 8) {
#pragma unroll
            for (int k = 0; k < 8; k++) *(v2f*)&xch[sidx * 18 + 2 * k] = Q[oc + k];
            __syncthreads();
#pragma unroll
            for (int k = 0; k < 8; k++) {
                const int o = oc + k;
                v2f qt = *(const v2f*)&xch[ridx * 18 + 2 * k];
                v2f v = P[o] + qt + RiI[o][ti] + CjJ[o][tj];
                if (dgl) v += ld2(DmA + 2 * ((b * OO + o) * NN + gi));
                nt_storev(&out2[((size_t)(b * OO + o) * NN + gi) * NN + gj], v);
            }
            __syncthreads();
        }
    }

    if (I == J) return;   // tile (J,I) identical, already written

    // ---- phase 2: out(J,I) = Q + P^T + terms ----
    {
        const int gi = J * 16 + ti, gj = I * 16 + tj;
        for (int oc = 0; oc < 16; oc += 8) {
#pragma unroll
            for (int k = 0; k < 8; k++) *(v2f*)&xch[sidx * 18 + 2 * k] = P[oc + k];
            __syncthreads();
#pragma unroll
            for (int k = 0; k < 8; k++) {
                const int o = oc + k;
                v2f pt = *(const v2f*)&xch[ridx * 18 + 2 * k];
                v2f v = Q[o] + pt + RiJ[o][ti] + CjI[o][tj];
                nt_storev(&out2[((size_t)(b * OO + o) * NN + gi) * NN + gj], v);
            }
            if (oc == 0) __syncthreads();   // last chunk needs no trailing barrier
        }
    }
}

extern "C" void kernel_launch(void* const* d_in, const int* in_sizes, int n_in,
                              void* d_out, int out_size, void* d_ws, size_t ws_size,
                              hipStream_t stream) {
    const float* in = (const float*)d_in[0];
    const float* w  = (const float*)d_in[1];
    float* out = (float*)d_out;
    float* ws  = (float*)d_ws;

    hipLaunchKernelGGL(k_reduce, dim3(BB * CC * 2), dim3(1024), 0, stream, in, ws);
    hipLaunchKernelGGL(k_terms,  dim3(BB * OO),     dim3(256),  0, stream, w, ws);
    hipLaunchKernelGGL(k_main,   dim3(BB * NPAIRS), dim3(256),  0, stream, in, w, out, ws);
}

// Round 6
// 266.549 us; speedup vs baseline: 1.0055x; 1.0055x over previous
//
#include <hip/hip_runtime.h>

#define NN 256
#define CC 16
#define OO 16
#define BB 16
#define NTILE 16
#define NPAIRS 136   // NTILE*(NTILE+1)/2

// workspace layout (float offsets)
#define OFF_DIAG 0         // B*C*N*2 = 131072
#define OFF_COL  131072
#define OFF_ROW  262144
#define OFF_TOT  393216    // B*C*2 = 512
#define OFF_DSUM 393728    // 512
#define OFF_RI   394496    // B*O*N*2 = 131072
#define OFF_CJ   525568
#define OFF_DM   656640
#define OFF_S0   787712    // 512

// nontemporal float2 helpers (bit-exact via double reinterpret)
__device__ __forceinline__ float2 nt_load2(const float2* p) {
    double d = __builtin_nontemporal_load((const double*)p);
    float2 r; *(double*)&r = d; return r;
}
__device__ __forceinline__ void nt_store2(float2* p, float2 v) {
    double d; *(float2*)&d = v;
    __builtin_nontemporal_store(d, (double*)p);
}

// ---------------------------------------------------------------------------
// Kernel 1: per-(b,c) reductions: diag, col_sum (over i), row_sum (over j),
// total sum, diag sum. One 1024-thread block per (b,c) slice (512 KiB).
// Normal (caching) loads on purpose: this pass populates L3 for k_main.
// ---------------------------------------------------------------------------
__global__ __launch_bounds__(1024) void k_reduce(const float* __restrict__ in,
                                                 float* __restrict__ ws) {
    float* diagA = ws + OFF_DIAG;
    float* colA  = ws + OFF_COL;
    float* rowA  = ws + OFF_ROW;
    float* totA  = ws + OFF_TOT;
    float* dsumA = ws + OFF_DSUM;

    const int bc  = blockIdx.x;            // b*C + c
    const int tid = threadIdx.x;
    const int wv  = tid >> 6;              // wave 0..15
    const int ln  = tid & 63;

    const float* base = in + (size_t)bc * (NN * NN * 2);

    __shared__ float colLDS[16][512];
    __shared__ float rowLDS[512];
    __shared__ float diagLDS[512];
    __shared__ float redT[16][2];
    __shared__ float redD[16][2];

    float a0 = 0, a1 = 0, a2 = 0, a3 = 0;
    float b0 = 0, b1 = 0, b2 = 0, b3 = 0;
    float dsx = 0, dsy = 0;

    for (int i = wv; i < NN; i += 16) {
        const float4* rowp = (const float4*)(base + i * (NN * 2));
        float4 v0 = rowp[ln];
        float4 v1 = rowp[64 + ln];
        a0 += v0.x; a1 += v0.y; a2 += v0.z; a3 += v0.w;
        b0 += v1.x; b1 += v1.y; b2 += v1.z; b3 += v1.w;
        float sx = v0.x + v0.z + v1.x + v1.z;
        float sy = v0.y + v0.w + v1.y + v1.w;
#pragma unroll
        for (int off = 32; off >= 1; off >>= 1) {
            sx += __shfl_xor(sx, off);
            sy += __shfl_xor(sy, off);
        }
        if (ln == 0) { rowLDS[i * 2] = sx; rowLDS[i * 2 + 1] = sy; }
        int k4 = i >> 1;
        if (ln == (k4 & 63)) {
            float4 dv = (k4 >> 6) ? v1 : v0;
            float dx = (i & 1) ? dv.z : dv.x;
            float dy = (i & 1) ? dv.w : dv.y;
            diagLDS[i * 2] = dx; diagLDS[i * 2 + 1] = dy;
            dsx += dx; dsy += dy;
        }
    }
    colLDS[wv][4 * ln]       = a0; colLDS[wv][4 * ln + 1]       = a1;
    colLDS[wv][4 * ln + 2]   = a2; colLDS[wv][4 * ln + 3]       = a3;
    colLDS[wv][256 + 4 * ln]     = b0; colLDS[wv][256 + 4 * ln + 1] = b1;
    colLDS[wv][256 + 4 * ln + 2] = b2; colLDS[wv][256 + 4 * ln + 3] = b3;

#pragma unroll
    for (int off = 32; off >= 1; off >>= 1) {
        dsx += __shfl_xor(dsx, off);
        dsy += __shfl_xor(dsy, off);
    }
    if (ln == 0) { redD[wv][0] = dsx; redD[wv][1] = dsy; }
    __syncthreads();

    float totpart = 0.f;
    if (tid < 512) {
        float s = 0.f;
#pragma unroll
        for (int w2 = 0; w2 < 16; w2++) s += colLDS[w2][tid];
        colA[bc * 512 + tid]  = s;
        rowA[bc * 512 + tid]  = rowLDS[tid];
        diagA[bc * 512 + tid] = diagLDS[tid];
        totpart = s;
    }
#pragma unroll
    for (int off = 32; off >= 2; off >>= 1) totpart += __shfl_xor(totpart, off);
    if (ln < 2) redT[wv][ln] = totpart;
    __syncthreads();
    if (tid == 0) {
        float t0 = 0, t1 = 0, d0 = 0, d1 = 0;
        for (int w2 = 0; w2 < 16; w2++) {
            t0 += redT[w2][0]; t1 += redT[w2][1];
            d0 += redD[w2][0]; d1 += redD[w2][1];
        }
        totA[bc * 2]  = t0; totA[bc * 2 + 1]  = t1;
        dsumA[bc * 2] = d0; dsumA[bc * 2 + 1] = d1;
    }
}

// ---------------------------------------------------------------------------
// Kernel 2: build broadcast terms Ri, Cj, Dm (B,O,N,2) and S0 (B,O,2).
// ---------------------------------------------------------------------------
__global__ __launch_bounds__(256) void k_terms(const float* __restrict__ w,
                                               float* __restrict__ ws) {
    const float* diagA = ws + OFF_DIAG;
    const float* colA  = ws + OFF_COL;
    const float* rowA  = ws + OFF_ROW;
    const float* totA  = ws + OFF_TOT;
    const float* dsumA = ws + OFF_DSUM;
    float* RiA = ws + OFF_RI;
    float* CjA = ws + OFF_CJ;
    float* DmA = ws + OFF_DM;
    float* S0A = ws + OFF_S0;

    const int b = blockIdx.x >> 4;
    const int o = blockIdx.x & 15;
    const int m = threadIdx.x;

    __shared__ float wL[CC][15];
    if (m < CC * 15) wL[m / 15][m % 15] = w[(m / 15) * (OO * 15) + o * 15 + m % 15];
    __syncthreads();

    float rix = 0, riy = 0, cjx = 0, cjy = 0, dmx = 0, dmy = 0;
    float s0x = 0, s0y = 0, dcx = 0, dcy = 0;
#pragma unroll
    for (int c = 0; c < CC; c++) {
        int bcm = (b * CC + c) * NN + m;
        float2 dg = ((const float2*)diagA)[bcm];
        float2 cs = ((const float2*)colA)[bcm];
        float2 rs = ((const float2*)rowA)[bcm];
        float w4 = wL[c][4], w5 = wL[c][5], w6 = wL[c][6];
        float w7 = wL[c][7], w8 = wL[c][8], w9 = wL[c][9];
        float wa = wL[c][10], wb = wL[c][11], wc = wL[c][12];
        rix += w6 * dg.x + w9 * cs.x + wc * rs.x;
        riy += w6 * dg.y + w9 * cs.y + wc * rs.y;
        cjx += w5 * dg.x + w8 * cs.x + wb * rs.x;
        cjy += w5 * dg.y + w8 * cs.y + wb * rs.y;
        dmx += w4 * dg.x + w7 * cs.x + wa * rs.x;
        dmy += w4 * dg.y + w7 * cs.y + wa * rs.y;
        float2 tt = ((const float2*)totA)[b * CC + c];
        float2 dd = ((const float2*)dsumA)[b * CC + c];
        float vx = dd.x * (1.0f / NN) + tt.x;
        float vy = dd.y * (1.0f / NN) + tt.y;
        s0x += wL[c][0] * vx; s0y += wL[c][0] * vy;
        dcx += wL[c][1] * vx; dcy += wL[c][1] * vy;
    }
    int om = (b * OO + o) * NN + m;
    ((float2*)RiA)[om] = make_float2(rix, riy);
    ((float2*)CjA)[om] = make_float2(cjx, cjy);
    ((float2*)DmA)[om] = make_float2(dmx + dcx, dmy + dcy);
    if (m == 0) ((float2*)S0A)[b * OO + o] = make_float2(s0x, s0y);
}

// ---------------------------------------------------------------------------
// Kernel 3: main pass. One block per (b, tile-pair (I,J), I<=J).
// NT loads for input (last use — input stays L3-resident anyway) and
// NT stores for output (streaming; keeps output from evicting the
// L3-resident input, which otherwise forces late-tile reads back to HBM).
// ---------------------------------------------------------------------------
__global__ __launch_bounds__(256) void k_main(const float* __restrict__ in,
                                              const float* __restrict__ w,
                                              float* __restrict__ out,
                                              const float* __restrict__ ws) {
    const float* RiA  = ws + OFF_RI;
    const float* CjA  = ws + OFF_CJ;
    const float* DmA  = ws + OFF_DM;
    const float* S0A  = ws + OFF_S0;

    const int b = blockIdx.x / NPAIRS;
    int p = blockIdx.x % NPAIRS;
    int I = 0;
    { int cnt = NTILE; while (p >= cnt) { p -= cnt; cnt--; I++; } }
    const int J = I + p;

    const int tid = threadIdx.x;
    const int ti = tid >> 4;
    const int tj = tid & 15;

    __shared__ float  xch[256 * 34];
    __shared__ float  wsm[256];           // w13 [c][o]
    __shared__ float2 s0L[16];
    __shared__ float2 RiI[16][16];
    __shared__ float2 CjJ[16][16];
    __shared__ float2 RiJ[16][16];
    __shared__ float2 CjI[16][16];

    {
        wsm[tid] = w[tid * 15 + 13];
        RiI[ti][tj] = ((const float2*)RiA)[(b * OO + ti) * NN + I * 16 + tj];
        CjJ[ti][tj] = ((const float2*)CjA)[(b * OO + ti) * NN + J * 16 + tj];
        if (I != J) {
            RiJ[ti][tj] = ((const float2*)RiA)[(b * OO + ti) * NN + J * 16 + tj];
            CjI[ti][tj] = ((const float2*)CjA)[(b * OO + ti) * NN + I * 16 + tj];
        }
        if (tid < 16) s0L[tid] = ((const float2*)S0A)[b * OO + tid];
    }
    __syncthreads();

    float2 P[16], Q[16];
#pragma unroll
    for (int o = 0; o < 16; o++) { P[o] = make_float2(0.f, 0.f); Q[o] = make_float2(0.f, 0.f); }

    const float2* pA = (const float2*)in + ((b * CC) * NN + I * 16 + ti) * NN + J * 16 + tj;
    const float2* pB = (const float2*)in + ((b * CC) * NN + J * 16 + ti) * NN + I * 16 + tj;

#pragma unroll 8
    for (int c = 0; c < CC; c++) {
        float2 a  = nt_load2(&pA[c * (NN * NN)]);
        float2 bb = nt_load2(&pB[c * (NN * NN)]);
#pragma unroll
        for (int o = 0; o < 16; o++) {
            float wv = wsm[c * 16 + o];
            P[o].x += wv * a.x;  P[o].y += wv * a.y;
            Q[o].x += wv * bb.x; Q[o].y += wv * bb.y;
        }
    }

    const int sidx = ti * 16 + (tj ^ ti);
    const int ridx = tj * 16 + (ti ^ tj);
    const bool dgl = (I == J) && (ti == tj);

    // ---- phase 1: out(I,J) = P + Q^T + terms ----
#pragma unroll
    for (int o = 0; o < 16; o++) *(float2*)&xch[sidx * 34 + o * 2] = Q[o];
    __syncthreads();
    {
        const int gi = I * 16 + ti, gj = J * 16 + tj;
#pragma unroll
        for (int o = 0; o < 16; o++) {
            float2 qt = *(const float2*)&xch[ridx * 34 + o * 2];
            float2 s0 = s0L[o];
            float2 ri = RiI[o][ti];
            float2 cj = CjJ[o][tj];
            float vx = P[o].x + qt.x + s0.x + ri.x + cj.x;
            float vy = P[o].y + qt.y + s0.y + ri.y + cj.y;
            if (dgl) {
                float2 dm = ((const float2*)DmA)[(b * OO + o) * NN + gi];
                vx += dm.x; vy += dm.y;
            }
            nt_store2(((float2*)out) + ((b * OO + o) * NN + gi) * NN + gj,
                      make_float2(vx, vy));
        }
    }

    if (I == J) return;   // P==Q: tile (J,I) identical, already written

    __syncthreads();

    // ---- phase 2: out(J,I) = Q + P^T + terms ----
#pragma unroll
    for (int o = 0; o < 16; o++) *(float2*)&xch[sidx * 34 + o * 2] = P[o];
    __syncthreads();
    {
        const int gi = J * 16 + ti, gj = I * 16 + tj;
#pragma unroll
        for (int o = 0; o < 16; o++) {
            float2 pt = *(const float2*)&xch[ridx * 34 + o * 2];
            float2 s0 = s0L[o];
            float2 ri = RiJ[o][ti];
            float2 cj = CjI[o][tj];
            float vx = Q[o].x + pt.x + s0.x + ri.x + cj.x;
            float vy = Q[o].y + pt.y + s0.y + ri.y + cj.y;
            nt_store2(((float2*)out) + ((b * OO + o) * NN + gi) * NN + gj,
                      make_float2(vx, vy));
        }
    }
}

extern "C" void kernel_launch(void* const* d_in, const int* in_sizes, int n_in,
                              void* d_out, int out_size, void* d_ws, size_t ws_size,
                              hipStream_t stream) {
    const float* in = (const float*)d_in[0];
    const float* w  = (const float*)d_in[1];
    float* out = (float*)d_out;
    float* ws  = (float*)d_ws;

    hipLaunchKernelGGL(k_reduce, dim3(BB * CC), dim3(1024), 0, stream, in, ws);
    hipLaunchKernelGGL(k_terms,  dim3(BB * OO), dim3(256),  0, stream, w, ws);
    hipLaunchKernelGGL(k_main,   dim3(BB * NPAIRS), dim3(256), 0, stream, in, w, out, ws);
}